// Round 1
// baseline (3208.706 us; speedup 1.0000x reference)
//
#include <hip/hip_runtime.h>
#include <hip/hip_bf16.h>

// Shapes (fixed by the reference): B=32, T=2048, D=512, H=128.
#define Bx 32
#define Tt 2048
#define Dd 512
#define Hh 128

// ---------------------------------------------------------------------------
// Phase 1: G[b,t,g,j] = sum_d x[b,t,d] * W_g[d,j]
// As a GEMM: M = B*T = 65536, K = D = 512, N = 4*H = 512 (gates concatenated).
// 64x64 tile, 256 threads, 4x4 micro-tile, K-tile 16.
// ---------------------------------------------------------------------------
__global__ __launch_bounds__(256) void gemm_xw(
    const float* __restrict__ X,
    const float* __restrict__ W0, const float* __restrict__ W1,
    const float* __restrict__ W2, const float* __restrict__ W3,
    float* __restrict__ G)
{
    __shared__ __align__(16) float As[16][68];   // [k][m], padded: stride 272B (16B-aligned, conflict-lite)
    __shared__ __align__(16) float Bs[16][64];   // [k][n]

    const int tid = threadIdx.x;
    const int n0 = blockIdx.x * 64;          // 0..511, tile stays inside one gate (64 | 128)
    const int m0 = blockIdx.y * 64;

    const int gate = n0 >> 7;
    const int jj0  = n0 & 127;
    const float* __restrict__ W = (gate == 0) ? W0 : (gate == 1) ? W1 : (gate == 2) ? W2 : W3;

    const int ac = tid & 15, ar = tid >> 4;  // A-load: col(k) 0..15, row 0..15 (x4)
    const int bn = tid & 63, bk = tid >> 6;  // B-load: col(n) 0..63, k 0..3 (x4)
    const int tx = tid & 15, ty = tid >> 4;  // compute: 16x16 threads

    float acc[4][4] = {};

    for (int k0 = 0; k0 < Dd; k0 += 16) {
        #pragma unroll
        for (int rr = 0; rr < 4; ++rr)
            As[ac][ar + rr * 16] = X[(size_t)(m0 + ar + rr * 16) * Dd + k0 + ac];
        #pragma unroll
        for (int kk = 0; kk < 4; ++kk)
            Bs[bk + kk * 4][bn] = W[(k0 + bk + kk * 4) * Hh + jj0 + bn];
        __syncthreads();

        #pragma unroll
        for (int k = 0; k < 16; ++k) {
            float4 a4 = *(const float4*)&As[k][ty * 4];
            float4 b4 = *(const float4*)&Bs[k][tx * 4];
            float a[4] = {a4.x, a4.y, a4.z, a4.w};
            float b[4] = {b4.x, b4.y, b4.z, b4.w};
            #pragma unroll
            for (int i = 0; i < 4; ++i)
                #pragma unroll
                for (int q = 0; q < 4; ++q)
                    acc[i][q] += a[i] * b[q];
        }
        __syncthreads();
    }

    #pragma unroll
    for (int i = 0; i < 4; ++i) {
        float4 r = make_float4(acc[i][0], acc[i][1], acc[i][2], acc[i][3]);
        *(float4*)&G[(size_t)(m0 + ty * 4 + i) * 512 + n0 + tx * 4] = r;
    }
}

// ---------------------------------------------------------------------------
// Phase 2: sequential scan. One block per batch element, 512 threads:
// thread (g = tid>>7, j = tid&127) computes gate g, column j.
// U_g[:,j] lives in 128 VGPRs; h in LDS; c in registads of tid<128.
// ---------------------------------------------------------------------------
__global__ __launch_bounds__(512) void lstm_scan(
    const float* __restrict__ G,
    const float* __restrict__ Uf, const float* __restrict__ Ui,
    const float* __restrict__ Uo, const float* __restrict__ Uc,
    const float* __restrict__ bf_, const float* __restrict__ bi_,
    const float* __restrict__ bo_, const float* __restrict__ bc_,
    const float* __restrict__ lnfg, const float* __restrict__ lnfb,
    const float* __restrict__ lnig, const float* __restrict__ lnib,
    const float* __restrict__ lnog, const float* __restrict__ lnob,
    const float* __restrict__ lncg, const float* __restrict__ lncb,
    const float* __restrict__ h0, const float* __restrict__ c0,
    const int* __restrict__ zmask,
    float* __restrict__ out, float* __restrict__ hT)
{
    const int b   = blockIdx.x;
    const int tid = threadIdx.x;
    const int g   = tid >> 7;
    const int j   = tid & 127;
    const int wave = tid >> 6;   // 0..7; gate g owns waves 2g, 2g+1

    const float* __restrict__ U  = (g == 0) ? Uf : (g == 1) ? Ui : (g == 2) ? Uo : Uc;
    const float* __restrict__ bg = (g == 0) ? bf_ : (g == 1) ? bi_ : (g == 2) ? bo_ : bc_;
    const float* __restrict__ lg = (g == 0) ? lnfg : (g == 1) ? lnig : (g == 2) ? lnog : lncg;
    const float* __restrict__ lb = (g == 0) ? lnfb : (g == 1) ? lnib : (g == 2) ? lnob : lncb;

    float u[Hh];
    #pragma unroll
    for (int k = 0; k < Hh; ++k) u[k] = U[k * Hh + j];
    const float bb  = bg[j];
    const float gam = lg[j];
    const float bet = lb[j];

    __shared__ __align__(16) float h_sh[Hh];
    __shared__ float gates[512];
    __shared__ float redS[8], redQ[8];

    if (tid < Hh) h_sh[tid] = h0[b * Hh + tid];
    float c = (tid < Hh) ? c0[b * Hh + tid] : 0.f;
    __syncthreads();

    const float* __restrict__ Gb   = G   + (size_t)b * Tt * 512;
    float* __restrict__       outb = out + (size_t)b * Tt * Hh;

    for (int t = 0; t < Tt; ++t) {
        // s = xW + b + h @ U  (column j of gate g)
        float s = Gb[t * 512 + tid] + bb;
        #pragma unroll
        for (int k = 0; k < Hh; k += 4) {
            float4 h4 = *(const float4*)&h_sh[k];
            s += h4.x * u[k] + h4.y * u[k + 1] + h4.z * u[k + 2] + h4.w * u[k + 3];
        }

        // LayerNorm reduction over the gate's 128 threads (= 2 waves)
        float sm = s, sq = s * s;
        #pragma unroll
        for (int off = 32; off > 0; off >>= 1) {
            sm += __shfl_xor(sm, off);
            sq += __shfl_xor(sq, off);
        }
        if ((tid & 63) == 0) { redS[wave] = sm; redQ[wave] = sq; }
        __syncthreads();
        float tS = redS[g * 2] + redS[g * 2 + 1];
        float tQ = redQ[g * 2] + redQ[g * 2 + 1];
        float mu  = tS * (1.f / 128.f);
        float var = tQ * (1.f / 128.f) - mu * mu;
        float xn  = (s - mu) * rsqrtf(var + 1e-5f) * gam + bet;
        float v   = 1.f / (1.f + __expf(-xn));
        gates[tid] = v;
        __syncthreads();

        if (tid < Hh) {
            float f  = gates[j];
            float i  = gates[128 + j];
            float o  = gates[256 + j];
            float ch = gates[384 + j];
            int   mt = zmask[t];
            float hn;
            if (mt) {
                hn = h_sh[j];           // zoneout: carry h, c unchanged
            } else {
                c  = f * c + i * ch;
                hn = o * (1.f / (1.f + __expf(-c)));   // NB: sigmoid, not tanh
                h_sh[j] = hn;
            }
            outb[t * Hh + j] = hn;
        }
        __syncthreads();
    }

    if (tid < Hh) hT[b * Hh + tid] = h_sh[tid];
}

// ---------------------------------------------------------------------------
extern "C" void kernel_launch(void* const* d_in, const int* in_sizes, int n_in,
                              void* d_out, int out_size, void* d_ws, size_t ws_size,
                              hipStream_t stream)
{
    const float* x   = (const float*)d_in[0];
    const float* W_f = (const float*)d_in[1];
    const float* W_i = (const float*)d_in[2];
    const float* W_o = (const float*)d_in[3];
    const float* W_c = (const float*)d_in[4];
    const float* U_f = (const float*)d_in[5];
    const float* U_i = (const float*)d_in[6];
    const float* U_o = (const float*)d_in[7];
    const float* U_c = (const float*)d_in[8];
    const float* b_f = (const float*)d_in[9];
    const float* b_i = (const float*)d_in[10];
    const float* b_o = (const float*)d_in[11];
    const float* b_c = (const float*)d_in[12];
    const float* ln_f_g = (const float*)d_in[13];
    const float* ln_f_b = (const float*)d_in[14];
    const float* ln_i_g = (const float*)d_in[15];
    const float* ln_i_b = (const float*)d_in[16];
    const float* ln_o_g = (const float*)d_in[17];
    const float* ln_o_b = (const float*)d_in[18];
    const float* ln_c_g = (const float*)d_in[19];
    const float* ln_c_b = (const float*)d_in[20];
    const float* h0  = (const float*)d_in[21];
    const float* c0  = (const float*)d_in[22];
    const int*   zm  = (const int*)d_in[23];

    float* out = (float*)d_out;                       // [B, T, H]
    float* hT  = out + (size_t)Bx * Tt * Hh;          // [B, H]
    float* G   = (float*)d_ws;                        // [B*T, 512] = 128 MiB

    dim3 gg(512 / 64, (Bx * Tt) / 64);                // 8 x 1024
    gemm_xw<<<gg, 256, 0, stream>>>(x, W_f, W_i, W_o, W_c, G);

    lstm_scan<<<Bx, 512, 0, stream>>>(G, U_f, U_i, U_o, U_c,
                                      b_f, b_i, b_o, b_c,
                                      ln_f_g, ln_f_b, ln_i_g, ln_i_b,
                                      ln_o_g, ln_o_b, ln_c_g, ln_c_b,
                                      h0, c0, zm, out, hT);
}